// Round 3
// baseline (139.580 us; speedup 1.0000x reference)
//
#include <hip/hip_runtime.h>

// VectorQuantizer: z_e [16,1024,256] f32, codebook [1024,256] f32
// out = concat( z_q [16,1024,256] f32 , indices [16,1024] as f32 )
// score(r,c) = ||c||^2 - 2*dot(z_r,c); argmin over c.
//
// R3 structure: A (z rows) staged once per block in LDS (XOR-swizzled, no
// k-loop barriers); B (codebook) read as wave-uniform SCALAR loads from a
// transposed copy cbT[k][c] so the FMA inner loop is pure
// v_fmac_f32 acc, s_b, v_z  (1 SGPR operand, no LDS traffic for B).

#define M_ROWS 16384
#define DDIM   256
#define NCODES 1024

__device__ __forceinline__ unsigned int f2ord(float f) {
    unsigned int u = __float_as_uint(f);
    return (u & 0x80000000u) ? ~u : (u | 0x80000000u);
}

// ---------------- init row minima ----------------
__global__ __launch_bounds__(256) void vq_init_kernel(unsigned long long* __restrict__ rowmin) {
    rowmin[blockIdx.x * 256 + threadIdx.x] = ~0ULL;
}

// ---------------- c_sq: one wave per code ----------------
__global__ __launch_bounds__(256) void vq_csq_kernel(const float* __restrict__ cb,
                                                     float* __restrict__ csq) {
    const int code = blockIdx.x * 4 + (threadIdx.x >> 6);
    const int lane = threadIdx.x & 63;
    const float4 v = *reinterpret_cast<const float4*>(cb + code * DDIM + lane * 4);
    float s = v.x * v.x + v.y * v.y + v.z * v.z + v.w * v.w;
#pragma unroll
    for (int off = 32; off > 0; off >>= 1) s += __shfl_down(s, off, 64);
    if (lane == 0) csq[code] = s;
}

// ---------------- transpose codebook: cbT[k][c] = cb[c][k] ----------------
__global__ __launch_bounds__(1024) void vq_transpose_kernel(const float* __restrict__ cb,
                                                            float* __restrict__ cbT) {
    const int k = blockIdx.x;        // 0..255
    const int c = threadIdx.x;       // 0..1023
    cbT[k * NCODES + c] = cb[c * DDIM + k];   // writes coalesced
}

// ---------------- main: scores + argmin ----------------
// grid (256 row-groups, 4 code-groups), 512 threads = 8 waves.
// Wave w owns codes [blockIdx.y*256 + w*32, +32). Lane = row within the
// block's 64-row group. acc[32] per lane. One barrier total.
__global__ __launch_bounds__(512, 4) void vq_score_kernel(const float* __restrict__ z,
                                                          const float* __restrict__ cbT,
                                                          const float* __restrict__ csq,
                                                          unsigned long long* __restrict__ rowmin) {
    __shared__ __align__(16) float As[64 * 256];   // 64 KB, [row][k] XOR-swizzled

    const int tid = threadIdx.x;
    const int rowBase = blockIdx.x * 64;

    // ---- stage A once: 64 rows x 256 k, swizzle k4 ^= (row & 31) ----
    {
        const int r   = tid >> 3;        // 0..63
        const int k40 = tid & 7;
        const float* zr = z + (size_t)(rowBase + r) * DDIM;
        const int swz = r & 31;
#pragma unroll
        for (int i = 0; i < 8; ++i) {
            const int k4 = k40 + i * 8;
            const float4 v = *reinterpret_cast<const float4*>(zr + k4 * 4);
            *reinterpret_cast<float4*>(&As[r * 256 + ((k4 ^ swz) * 4)]) = v;
        }
    }
    __syncthreads();

    const int lane = tid & 63;
    const int wv   = __builtin_amdgcn_readfirstlane(tid >> 6);   // 0..7, wave-uniform
    const int c0   = blockIdx.y * 256 + wv * 32;
    const float* __restrict__ bbase = cbT + c0;

    // acc[c] = dot(z_row, code_c) - csq[c]/2 ; argmin score == argmax acc
    float acc[32];
#pragma unroll
    for (int c = 0; c < 32; ++c) acc[c] = csq[c0 + c] * -0.5f;

    const int rbase = lane * 256;
    const int swz   = lane & 31;

#pragma unroll 2
    for (int k4 = 0; k4 < 64; ++k4) {
        const float4 vz = *reinterpret_cast<const float4*>(&As[rbase + ((k4 ^ swz) * 4)]);
        const float* bk = bbase + k4 * 4 * NCODES;
        {
            const float* b = bk;
#pragma unroll
            for (int c = 0; c < 32; ++c) acc[c] = fmaf(vz.x, b[c], acc[c]);
        }
        {
            const float* b = bk + NCODES;
#pragma unroll
            for (int c = 0; c < 32; ++c) acc[c] = fmaf(vz.y, b[c], acc[c]);
        }
        {
            const float* b = bk + 2 * NCODES;
#pragma unroll
            for (int c = 0; c < 32; ++c) acc[c] = fmaf(vz.z, b[c], acc[c]);
        }
        {
            const float* b = bk + 3 * NCODES;
#pragma unroll
            for (int c = 0; c < 32; ++c) acc[c] = fmaf(vz.w, b[c], acc[c]);
        }
    }

    // per-lane argmax(acc) -> sortable min-key (score order), tie -> min idx
    unsigned long long key = ~0ULL;
#pragma unroll
    for (int c = 0; c < 32; ++c) {
        const unsigned long long k =
            ((unsigned long long)f2ord(-acc[c]) << 32) | (unsigned int)(c0 + c);
        key = (k < key) ? k : key;
    }
    atomicMin(&rowmin[rowBase + lane], key);
}

// ---------------- gather z_q = codebook[idx], emit indices ----------------
__global__ __launch_bounds__(256) void vq_gather_kernel(const float* __restrict__ cb,
                                                        const unsigned long long* __restrict__ rowmin,
                                                        float* __restrict__ zq,
                                                        float* __restrict__ outIdx) {
    const int row  = blockIdx.x * 4 + (threadIdx.x >> 6);
    const int lane = threadIdx.x & 63;
    const int idx  = (int)(unsigned int)(rowmin[row] & 0xFFFFFFFFULL);
    if (lane == 0) outIdx[row] = (float)idx;
    const float4 v = *reinterpret_cast<const float4*>(cb + (size_t)idx * DDIM + lane * 4);
    *reinterpret_cast<float4*>(zq + (size_t)row * DDIM + lane * 4) = v;
}

extern "C" void kernel_launch(void* const* d_in, const int* in_sizes, int n_in,
                              void* d_out, int out_size, void* d_ws, size_t ws_size,
                              hipStream_t stream) {
    const float* z  = (const float*)d_in[0];   // [16,1024,256]
    const float* cb = (const float*)d_in[1];   // [1024,256]
    float* out    = (float*)d_out;
    float* zq     = out;                           // 16*1024*256 floats
    float* outIdx = out + (size_t)M_ROWS * DDIM;   // 16384 floats

    unsigned long long* rowmin = (unsigned long long*)d_ws;             // 128 KB
    float* csq = (float*)((char*)d_ws + (size_t)M_ROWS * 8);            // 4 KB
    float* cbT = (float*)((char*)d_ws + (size_t)M_ROWS * 8 + 4096);     // 1 MB

    vq_init_kernel<<<M_ROWS / 256, 256, 0, stream>>>(rowmin);
    vq_csq_kernel<<<NCODES / 4, 256, 0, stream>>>(cb, csq);
    vq_transpose_kernel<<<DDIM, 1024, 0, stream>>>(cb, cbT);

    dim3 grid(M_ROWS / 64, NCODES / 256);
    vq_score_kernel<<<grid, 512, 0, stream>>>(z, cbT, csq, rowmin);

    vq_gather_kernel<<<M_ROWS / 4, 256, 0, stream>>>(cb, rowmin, zq, outIdx);
}

// Round 4
// 89.945 us; speedup vs baseline: 1.5518x; 1.5518x over previous
//
#include <hip/hip_runtime.h>

// VectorQuantizer via fp16-MFMA filter + exact fp32 rescore.
// z_e [16,1024,256] f32, codebook [1024,256] f32
// out = concat( z_q [16,1024,256] f32 , indices [16,1024] as f32 )
//
// 1. pack: z,cb -> fp16 in MFMA-fragment order (granule = 16 rows x 32 k,
//    elem(lane,j) = X[g16 + (lane&15)][k32 + (lane>>4)*8 + j])
// 2. csq exact fp32
// 3. score: 64x64 tile per wave, 16x16x32 f16 MFMA, no LDS/barriers.
//    Epilogue: top-2 candidate codes per row per 64-code block -> cand[row][32]
// 4. final: exact fp32 rescore of 32 candidates/row, argmin, gather z_q.

#define M_ROWS 16384
#define DDIM   256
#define NCODES 1024

typedef _Float16 half8 __attribute__((ext_vector_type(8)));
typedef float    f32x4 __attribute__((ext_vector_type(4)));

__device__ __forceinline__ unsigned int f2ord(float f) {
    unsigned int u = __float_as_uint(f);
    return (u & 0x80000000u) ? ~u : (u | 0x80000000u);
}

// ---------------- pack f32 -> fp16 fragment order ----------------
// gid = (rowTile*8 + kt)*64 + lane ; one thread emits 8 fp16 (16 B).
__global__ __launch_bounds__(256) void vq_pack_kernel(const float* __restrict__ src,
                                                      _Float16* __restrict__ dst) {
    const int gid = blockIdx.x * 256 + threadIdx.x;
    const int l   = gid & 63;
    const int g   = gid >> 6;          // rt*8 + kt
    const int kt  = g & 7;
    const int rt  = g >> 3;
    const int row = rt * 16 + (l & 15);
    const int k0  = kt * 32 + (l >> 4) * 8;
    const float4 v0 = *reinterpret_cast<const float4*>(src + (size_t)row * DDIM + k0);
    const float4 v1 = *reinterpret_cast<const float4*>(src + (size_t)row * DDIM + k0 + 4);
    half8 h;
    h[0] = (_Float16)v0.x; h[1] = (_Float16)v0.y; h[2] = (_Float16)v0.z; h[3] = (_Float16)v0.w;
    h[4] = (_Float16)v1.x; h[5] = (_Float16)v1.y; h[6] = (_Float16)v1.z; h[7] = (_Float16)v1.w;
    *reinterpret_cast<half8*>(dst + (size_t)gid * 8) = h;
}

// ---------------- c_sq exact (fp32) ----------------
__global__ __launch_bounds__(256) void vq_csq_kernel(const float* __restrict__ cb,
                                                     float* __restrict__ csq) {
    const int code = blockIdx.x * 4 + (threadIdx.x >> 6);
    const int lane = threadIdx.x & 63;
    const float4 v = *reinterpret_cast<const float4*>(cb + (size_t)code * DDIM + lane * 4);
    float s = v.x * v.x + v.y * v.y + v.z * v.z + v.w * v.w;
#pragma unroll
    for (int off = 32; off > 0; off >>= 1) s += __shfl_down(s, off, 64);
    if (lane == 0) csq[code] = s;
}

// ---------------- approx scores + top-2 per 64-code block ----------------
// One wave = one 64x64 tile. 4096 tiles: tileRow = t>>4 (0..255), tileCol = t&15.
__global__ __launch_bounds__(256) void vq_score_kernel(const _Float16* __restrict__ Ap,
                                                       const _Float16* __restrict__ Bp,
                                                       const float* __restrict__ csq,
                                                       unsigned long long* __restrict__ cand) {
    const int lane = threadIdx.x & 63;
    const int t    = blockIdx.x * 4 + (threadIdx.x >> 6);
    const int tileRow = t >> 4;
    const int tileCol = t & 15;
    const int rt0 = tileRow * 4;
    const int ct0 = tileCol * 4;

    const half8* __restrict__ A = reinterpret_cast<const half8*>(Ap);
    const half8* __restrict__ B = reinterpret_cast<const half8*>(Bp);

    f32x4 acc[4][4];
#pragma unroll
    for (int m = 0; m < 4; ++m)
#pragma unroll
        for (int n = 0; n < 4; ++n) acc[m][n] = (f32x4){0.f, 0.f, 0.f, 0.f};

#pragma unroll
    for (int kt = 0; kt < 8; ++kt) {
        half8 a[4], b[4];
#pragma unroll
        for (int m = 0; m < 4; ++m) a[m] = A[((rt0 + m) * 8 + kt) * 64 + lane];
#pragma unroll
        for (int n = 0; n < 4; ++n) b[n] = B[((ct0 + n) * 8 + kt) * 64 + lane];
#pragma unroll
        for (int m = 0; m < 4; ++m)
#pragma unroll
            for (int n = 0; n < 4; ++n)
                acc[m][n] = __builtin_amdgcn_mfma_f32_16x16x32_f16(a[m], b[n], acc[m][n], 0, 0, 0);
    }

    // epilogue: per row (16 slots of (m,reg)), top-2 keys across 64 cols
    const int colBase = tileCol * 64;
    const int rowBase = tileRow * 64;
    const int cx = lane & 15;
    const int q  = lane >> 4;
    float csv[4];
#pragma unroll
    for (int n = 0; n < 4; ++n) csv[n] = csq[colBase + n * 16 + cx];

#pragma unroll
    for (int m = 0; m < 4; ++m) {
#pragma unroll
        for (int r = 0; r < 4; ++r) {
            unsigned long long k0 = ~0ULL, k1 = ~0ULL;
#pragma unroll
            for (int n = 0; n < 4; ++n) {
                const float s = csv[n] - 2.0f * acc[m][n][r];
                const unsigned long long key =
                    ((unsigned long long)f2ord(s) << 32) | (unsigned)(colBase + n * 16 + cx);
                if (key < k0) { k1 = k0; k0 = key; }
                else if (key < k1) { k1 = key; }
            }
            // butterfly top-2 merge across the 16 lanes sharing this row
#pragma unroll
            for (int off = 1; off < 16; off <<= 1) {
                const unsigned long long o0 = __shfl_xor(k0, off, 64);
                const unsigned long long o1 = __shfl_xor(k1, off, 64);
                const unsigned long long lo = (k0 < o0) ? k0 : o0;
                const unsigned long long hi = (k0 < o0) ? o0 : k0;
                const unsigned long long m2 = (k1 < o1) ? k1 : o1;
                k1 = (hi < m2) ? hi : m2;
                k0 = lo;
            }
            if (cx == 0) {
                const int row = rowBase + m * 16 + q * 4 + r;
                ulonglong2 v; v.x = k0; v.y = k1;
                *reinterpret_cast<ulonglong2*>(&cand[(size_t)row * 32 + tileCol * 2]) = v;
            }
        }
    }
}

// ---------------- exact rescore of 32 candidates + gather ----------------
// One wave per 4 rows; 1024 blocks x 256 thr = 4096 waves.
__global__ __launch_bounds__(256) void vq_final_kernel(const float* __restrict__ z,
                                                       const float* __restrict__ cb,
                                                       const float* __restrict__ csq,
                                                       const unsigned long long* __restrict__ cand,
                                                       float* __restrict__ zq,
                                                       float* __restrict__ outIdx) {
    const int lane = threadIdx.x & 63;
    const int gw   = blockIdx.x * 4 + (threadIdx.x >> 6);   // 0..4095

#pragma unroll
    for (int i = 0; i < 4; ++i) {
        const int row = gw * 4 + i;
        const float4 zv = *reinterpret_cast<const float4*>(z + (size_t)row * DDIM + lane * 4);
        unsigned long long best = ~0ULL;
        for (int ci = 0; ci < 32; ++ci) {
            const int idx = (int)(unsigned)(cand[(size_t)row * 32 + ci] & 0xFFFFFFFFULL);
            const float4 cv = *reinterpret_cast<const float4*>(cb + (size_t)idx * DDIM + lane * 4);
            float p = zv.x * cv.x + zv.y * cv.y + zv.z * cv.z + zv.w * cv.w;
#pragma unroll
            for (int off = 1; off < 64; off <<= 1) p += __shfl_xor(p, off, 64);
            const float s = csq[idx] - 2.0f * p;
            const unsigned long long key = ((unsigned long long)f2ord(s) << 32) | (unsigned)idx;
            best = (key < best) ? key : best;
        }
        const int bi = (int)(unsigned)(best & 0xFFFFFFFFULL);
        if (lane == 0) outIdx[row] = (float)bi;
        const float4 q4 = *reinterpret_cast<const float4*>(cb + (size_t)bi * DDIM + lane * 4);
        *reinterpret_cast<float4*>(zq + (size_t)row * DDIM + lane * 4) = q4;
    }
}

extern "C" void kernel_launch(void* const* d_in, const int* in_sizes, int n_in,
                              void* d_out, int out_size, void* d_ws, size_t ws_size,
                              hipStream_t stream) {
    const float* z  = (const float*)d_in[0];   // [16384,256]
    const float* cb = (const float*)d_in[1];   // [1024,256]
    float* out    = (float*)d_out;
    float* zq     = out;                            // 16.77 MB
    float* outIdx = out + (size_t)M_ROWS * DDIM;    // 64 KB

    // zh_packed (8 MB) lives in the z_q region: read-only until vq_final
    // overwrites z_q (stream-ordered after vq_score).
    _Float16* zhp = (_Float16*)d_out;

    char* ws = (char*)d_ws;
    _Float16* chp = (_Float16*)ws;                               // 512 KB
    float* csq    = (float*)(ws + 512 * 1024);                   // 4 KB
    unsigned long long* cand =
        (unsigned long long*)(ws + 512 * 1024 + 4096);           // 4 MB

    vq_pack_kernel<<<(M_ROWS / 16) * 8 * 64 / 256, 256, 0, stream>>>(z, zhp);
    vq_pack_kernel<<<(NCODES / 16) * 8 * 64 / 256, 256, 0, stream>>>(cb, chp);
    vq_csq_kernel<<<NCODES / 4, 256, 0, stream>>>(cb, csq);
    vq_score_kernel<<<(M_ROWS / 64) * (NCODES / 64) / 4, 256, 0, stream>>>(zhp, chp, csq, cand);
    vq_final_kernel<<<M_ROWS / 16, 256, 0, stream>>>(z, cb, csq, cand, zq, outIdx);
}

// Round 5
// 44.064 us; speedup vs baseline: 3.1677x; 2.0413x over previous
//
#include <hip/hip_runtime.h>

// VectorQuantizer via fp16-MFMA filter + exact fp32 rescore (DPP cross-lane).
// z_e [16,1024,256] f32, codebook [1024,256] f32
// out = concat( z_q [16,1024,256] f32 , indices [16,1024] as f32 )
//
// 1. pack_z: z -> fp16 MFMA-fragment order (into d_out scratch region)
// 2. prep_cb: cb -> fp16 fragment order + exact fp32 csq
// 3. score: block = 64 rows x 256 cols (4 waves, A shared via LDS).
//    16x16x32 f16 MFMA; epilogue: u32 keys (truncated score | idx),
//    DPP row_shr top-2 merge, cross-wave LDS merge -> cand[row][8]
// 4. final: wave per row; 8 exact fp32 rescores with DPP add-reduce; gather.

#define M_ROWS 16384
#define DDIM   256
#define NCODES 1024

typedef _Float16 half8 __attribute__((ext_vector_type(8)));
typedef float    f32x4 __attribute__((ext_vector_type(4)));

__device__ __forceinline__ unsigned int f2ord(float f) {
    unsigned int u = __float_as_uint(f);
    return (u & 0x80000000u) ? ~u : (u | 0x80000000u);
}

// DPP move keeping own value on invalid lanes (for min-merges)
#define DPP_SELF(k, ctrl) \
    ((unsigned)__builtin_amdgcn_update_dpp((int)(k), (int)(k), (ctrl), 0xF, 0xF, false))
// DPP move with 0-fill on invalid lanes (for add-reduce)
#define DPP_Z(v, ctrl) \
    __builtin_amdgcn_update_dpp(0, (v), (ctrl), 0xF, 0xF, true)

// 64-lane sum via DPP; total valid in lane 63
__device__ __forceinline__ float dpp_radd(float x) {
    float s = x;
    s += __int_as_float(DPP_Z(__float_as_int(s), 0x111));  // row_shr:1
    s += __int_as_float(DPP_Z(__float_as_int(s), 0x112));  // row_shr:2
    s += __int_as_float(DPP_Z(__float_as_int(s), 0x114));  // row_shr:4
    s += __int_as_float(DPP_Z(__float_as_int(s), 0x118));  // row_shr:8
    s += __int_as_float(DPP_Z(__float_as_int(s), 0x142));  // row_bcast:15
    s += __int_as_float(DPP_Z(__float_as_int(s), 0x143));  // row_bcast:31
    return s;
}

// ---------------- pack z: f32 -> fp16 fragment order ----------------
__global__ __launch_bounds__(256) void vq_pack_kernel(const float* __restrict__ src,
                                                      _Float16* __restrict__ dst) {
    const int gid = blockIdx.x * 256 + threadIdx.x;
    const int l   = gid & 63;
    const int g   = gid >> 6;          // rt*8 + kt
    const int kt  = g & 7;
    const int rt  = g >> 3;
    const int row = rt * 16 + (l & 15);
    const int k0  = kt * 32 + (l >> 4) * 8;
    const float4 v0 = *reinterpret_cast<const float4*>(src + (size_t)row * DDIM + k0);
    const float4 v1 = *reinterpret_cast<const float4*>(src + (size_t)row * DDIM + k0 + 4);
    half8 h;
    h[0] = (_Float16)v0.x; h[1] = (_Float16)v0.y; h[2] = (_Float16)v0.z; h[3] = (_Float16)v0.w;
    h[4] = (_Float16)v1.x; h[5] = (_Float16)v1.y; h[6] = (_Float16)v1.z; h[7] = (_Float16)v1.w;
    *reinterpret_cast<half8*>(dst + (size_t)gid * 8) = h;
}

// ---------------- prep cb: pack (blocks 0..127) + csq (blocks 128..383) ----
__global__ __launch_bounds__(256) void vq_prep_cb(const float* __restrict__ cb,
                                                  _Float16* __restrict__ chp,
                                                  float* __restrict__ csq) {
    if (blockIdx.x < 128) {
        const int gid = blockIdx.x * 256 + threadIdx.x;
        const int l   = gid & 63;
        const int g   = gid >> 6;
        const int kt  = g & 7;
        const int rt  = g >> 3;
        const int row = rt * 16 + (l & 15);
        const int k0  = kt * 32 + (l >> 4) * 8;
        const float4 v0 = *reinterpret_cast<const float4*>(cb + (size_t)row * DDIM + k0);
        const float4 v1 = *reinterpret_cast<const float4*>(cb + (size_t)row * DDIM + k0 + 4);
        half8 h;
        h[0] = (_Float16)v0.x; h[1] = (_Float16)v0.y; h[2] = (_Float16)v0.z; h[3] = (_Float16)v0.w;
        h[4] = (_Float16)v1.x; h[5] = (_Float16)v1.y; h[6] = (_Float16)v1.z; h[7] = (_Float16)v1.w;
        *reinterpret_cast<half8*>(chp + (size_t)gid * 8) = h;
    } else {
        const int code = (blockIdx.x - 128) * 4 + (threadIdx.x >> 6);
        const int lane = threadIdx.x & 63;
        const float4 v = *reinterpret_cast<const float4*>(cb + (size_t)code * DDIM + lane * 4);
        float s = v.x * v.x + v.y * v.y + v.z * v.z + v.w * v.w;
        s = dpp_radd(s);
        if (lane == 63) csq[code] = s;
    }
}

// ---------------- score: approx scores + top-2 per 256-code block ----------
// grid (256 rowTiles, 4 colGroups) x 256 thr. Wave wv covers colTile cg*4+wv.
__global__ __launch_bounds__(256, 4) void vq_score_kernel(const _Float16* __restrict__ Ap,
                                                          const _Float16* __restrict__ Bp,
                                                          const float* __restrict__ csq,
                                                          unsigned* __restrict__ cand) {
    __shared__ __align__(16) _Float16 As[64 * 256];   // 32 KB, fragment-linear
    __shared__ uint2 red[4][64];

    const int tid  = threadIdx.x;
    const int lane = tid & 63;
    const int wv   = tid >> 6;
    const int rowTile = blockIdx.x;
    const int cg      = blockIdx.y;

    // stage A tile (32 KB contiguous in packed layout)
    {
        const uint4* src = reinterpret_cast<const uint4*>(Ap + (size_t)rowTile * 16384);
        uint4* dst = reinterpret_cast<uint4*>(As);
#pragma unroll
        for (int i = 0; i < 8; ++i) dst[i * 256 + tid] = src[i * 256 + tid];
    }
    __syncthreads();

    const int colTile = cg * 4 + wv;          // 0..15
    const half8* __restrict__ B = reinterpret_cast<const half8*>(Bp);

    f32x4 acc[4][4];
#pragma unroll
    for (int m = 0; m < 4; ++m)
#pragma unroll
        for (int n = 0; n < 4; ++n) acc[m][n] = (f32x4){0.f, 0.f, 0.f, 0.f};

#pragma unroll
    for (int kt = 0; kt < 8; ++kt) {
        half8 a[4], b[4];
#pragma unroll
        for (int m = 0; m < 4; ++m)
            a[m] = *reinterpret_cast<const half8*>(&As[((m * 8 + kt) * 64 + lane) * 8]);
#pragma unroll
        for (int n = 0; n < 4; ++n)
            b[n] = B[(size_t)(((colTile * 4 + n) * 8 + kt) * 64 + lane)];
#pragma unroll
        for (int m = 0; m < 4; ++m)
#pragma unroll
            for (int n = 0; n < 4; ++n)
                acc[m][n] = __builtin_amdgcn_mfma_f32_16x16x32_f16(a[m], b[n], acc[m][n], 0, 0, 0);
    }

    // epilogue: u32 key = (f2ord(score) & ~1023) | codeIdx ; top-2 per row
    const int cx = lane & 15;
    const int q  = lane >> 4;
    const int colBase = colTile * 64;
    float csv[4];
#pragma unroll
    for (int n = 0; n < 4; ++n) csv[n] = csq[colBase + n * 16 + cx];

#pragma unroll
    for (int m = 0; m < 4; ++m) {
#pragma unroll
        for (int r = 0; r < 4; ++r) {
            unsigned k0 = 0xFFFFFFFFu, k1 = 0xFFFFFFFFu;
#pragma unroll
            for (int n = 0; n < 4; ++n) {
                const float s = fmaf(-2.0f, acc[m][n][r], csv[n]);
                const unsigned key = (f2ord(s) & 0xFFFFFC00u)
                                   | (unsigned)(colBase + n * 16 + cx);
                if (key < k0) { k1 = k0; k0 = key; }
                else if (key < k1) { k1 = key; }
            }
            // DPP top-2 merge across the 16 lanes of this DPP row
#define MERGE_STEP(CTRL)                                              \
            {                                                         \
                const unsigned o0 = DPP_SELF(k0, CTRL);               \
                const unsigned o1 = DPP_SELF(k1, CTRL);               \
                const unsigned lo = (k0 < o0) ? k0 : o0;              \
                const unsigned hi = (k0 < o0) ? o0 : k0;              \
                const unsigned m1 = (k1 < o1) ? k1 : o1;              \
                k1 = (hi < m1) ? hi : m1;                             \
                k0 = lo;                                              \
            }
            MERGE_STEP(0x111)   // row_shr:1
            MERGE_STEP(0x112)   // row_shr:2
            MERGE_STEP(0x114)   // row_shr:4
            MERGE_STEP(0x118)   // row_shr:8
#undef MERGE_STEP
            if (cx == 15) red[wv][m * 16 + q * 4 + r] = make_uint2(k0, k1);
        }
    }
    __syncthreads();

    // cross-wave merge: 4 waves x 2 -> top-2 per row for this 256-col group
    if (tid < 64) {
        unsigned b0 = 0xFFFFFFFFu, b1 = 0xFFFFFFFFu;
#pragma unroll
        for (int w = 0; w < 4; ++w) {
            const uint2 v = red[w][tid];
            if (v.x < b0) { b1 = b0; b0 = v.x; } else if (v.x < b1) { b1 = v.x; }
            if (v.y < b0) { b1 = b0; b0 = v.y; } else if (v.y < b1) { b1 = v.y; }
        }
        const size_t row = (size_t)rowTile * 64 + tid;
        cand[row * 8 + cg * 2 + 0] = b0;
        cand[row * 8 + cg * 2 + 1] = b1;
    }
}

// ---------------- final: exact fp32 rescore of 8 candidates + gather -------
__global__ __launch_bounds__(256) void vq_final_kernel(const float* __restrict__ z,
                                                       const float* __restrict__ cb,
                                                       const float* __restrict__ csq,
                                                       const unsigned* __restrict__ cand,
                                                       float* __restrict__ zq,
                                                       float* __restrict__ outIdx) {
    const int lane = threadIdx.x & 63;
    const int row  = blockIdx.x * 4 + (threadIdx.x >> 6);

    const float4 zv = *reinterpret_cast<const float4*>(z + (size_t)row * DDIM + lane * 4);

    unsigned kk[8];
    *reinterpret_cast<uint4*>(&kk[0]) = *reinterpret_cast<const uint4*>(cand + (size_t)row * 8);
    *reinterpret_cast<uint4*>(&kk[4]) = *reinterpret_cast<const uint4*>(cand + (size_t)row * 8 + 4);

    float bestS = 3.4e38f;
    int   bestI = 0x7FFFFFFF;
#pragma unroll
    for (int c = 0; c < 8; ++c) {
        const int idx = (int)(kk[c] & 1023u);
        const float4 cv = *reinterpret_cast<const float4*>(cb + (size_t)idx * DDIM + lane * 4);
        float p = fmaf(zv.x, cv.x, fmaf(zv.y, cv.y, fmaf(zv.z, cv.z, zv.w * cv.w)));
        p = dpp_radd(p);                       // total in lane 63
        p = __shfl(p, 63, 64);                 // broadcast to all lanes
        const float s = fmaf(-2.0f, p, csq[idx]);
        if (s < bestS || (s == bestS && idx < bestI)) { bestS = s; bestI = idx; }
    }

    if (lane == 0) outIdx[row] = (float)bestI;
    const float4 q4 = *reinterpret_cast<const float4*>(cb + (size_t)bestI * DDIM + lane * 4);
    *reinterpret_cast<float4*>(zq + (size_t)row * DDIM + lane * 4) = q4;
}

extern "C" void kernel_launch(void* const* d_in, const int* in_sizes, int n_in,
                              void* d_out, int out_size, void* d_ws, size_t ws_size,
                              hipStream_t stream) {
    const float* z  = (const float*)d_in[0];   // [16384,256]
    const float* cb = (const float*)d_in[1];   // [1024,256]
    float* out    = (float*)d_out;
    float* zq     = out;                            // 16.77 MB
    float* outIdx = out + (size_t)M_ROWS * DDIM;    // 64 KB

    // packed z (8 MB) lives in the z_q output region: scratch until vq_final
    _Float16* zhp = (_Float16*)d_out;

    char* ws = (char*)d_ws;
    _Float16* chp = (_Float16*)ws;                              // 512 KB
    float* csq    = (float*)(ws + 512 * 1024);                  // 4 KB
    unsigned* cand = (unsigned*)(ws + 512 * 1024 + 4096);       // 512 KB

    vq_pack_kernel<<<2048, 256, 0, stream>>>(z, zhp);
    vq_prep_cb<<<384, 256, 0, stream>>>(cb, chp, csq);
    dim3 sg(M_ROWS / 64, 4);
    vq_score_kernel<<<sg, 256, 0, stream>>>(zhp, chp, csq, cand);
    vq_final_kernel<<<M_ROWS / 4, 256, 0, stream>>>(z, cb, csq, cand, zq, outIdx);
}